// Round 1
// baseline (1095.396 us; speedup 1.0000x reference)
//
#include <hip/hip_runtime.h>

#define NN      100000
#define NE      3200000
#define IN_DIM  256
#define HID     64
#define ODIM    32
#define SCAN_ITEMS 1024

// ---------------- edge dtype detection (int64 vs int32) ----------------
// jnp array is int64; harness contract says int32. Detect on device:
// int64 layout => odd dwords (high words) of first 256 values are all 0.
__global__ void k_detect(const unsigned* __restrict__ e, int* __restrict__ flag) {
    unsigned d = e[2u * threadIdx.x + 1u];
    if (d != 0u) atomicOr(flag, 1);   // any nonzero => int32 layout
}

__global__ void k_count(const void* __restrict__ ev, const int* __restrict__ flag,
                        int* __restrict__ cnt) {
    int e = blockIdx.x * blockDim.x + threadIdx.x;
    if (e >= NE) return;
    int d;
    if (*flag == 0) d = (int)((const long long*)ev)[(size_t)NE + e];
    else            d = ((const int*)ev)[(size_t)NE + e];
    atomicAdd(&cnt[d], 1);
}

__global__ void k_dinv(const int* __restrict__ cnt, float* __restrict__ dinv) {
    int i = blockIdx.x * blockDim.x + threadIdx.x;
    if (i < NN) dinv[i] = 1.0f / sqrtf((float)(cnt[i] + 1));  // +1 self-loop, deg>=1
}

// ---------------- exclusive scan of cnt -> rowptr ----------------
__global__ void k_scan1(const int* __restrict__ cnt, int* __restrict__ bsums) {
    __shared__ int s[256];
    int base = blockIdx.x * SCAN_ITEMS;
    int t = threadIdx.x;
    int sum = 0;
#pragma unroll
    for (int j = 0; j < 4; ++j) {
        int idx = base + t * 4 + j;
        if (idx < NN) sum += cnt[idx];
    }
    s[t] = sum; __syncthreads();
    for (int off = 128; off > 0; off >>= 1) {
        if (t < off) s[t] += s[t + off];
        __syncthreads();
    }
    if (t == 0) bsums[blockIdx.x] = s[0];
}

__global__ void k_scan2(int* __restrict__ bsums, int* __restrict__ rowptr, int nb) {
    if (threadIdx.x == 0 && blockIdx.x == 0) {
        int run = 0;
        for (int i = 0; i < nb; ++i) { int v = bsums[i]; bsums[i] = run; run += v; }
        rowptr[NN] = run;   // == NE
    }
}

__global__ void k_scan3(const int* __restrict__ cnt, const int* __restrict__ bsums,
                        int* __restrict__ rowptr, int* __restrict__ fillpos) {
    __shared__ int s[256];
    int base = blockIdx.x * SCAN_ITEMS;
    int t = threadIdx.x;
    int c[4]; int sum = 0;
#pragma unroll
    for (int j = 0; j < 4; ++j) {
        int idx = base + t * 4 + j;
        c[j] = (idx < NN) ? cnt[idx] : 0;
        sum += c[j];
    }
    s[t] = sum; __syncthreads();
    for (int off = 1; off < 256; off <<= 1) {       // Hillis-Steele inclusive
        int v = (t >= off) ? s[t - off] : 0;
        __syncthreads();
        if (t >= off) s[t] += v;
        __syncthreads();
    }
    int pos = bsums[blockIdx.x] + (s[t] - sum);     // exclusive offset
#pragma unroll
    for (int j = 0; j < 4; ++j) {
        int idx = base + t * 4 + j;
        if (idx < NN) { rowptr[idx] = pos; fillpos[idx] = pos; pos += c[j]; }
    }
}

__global__ void k_fill(const void* __restrict__ ev, const int* __restrict__ flag,
                       int* __restrict__ fillpos, int* __restrict__ csr) {
    int e = blockIdx.x * blockDim.x + threadIdx.x;
    if (e >= NE) return;
    int s, d;
    if (*flag == 0) {
        s = (int)((const long long*)ev)[e];
        d = (int)((const long long*)ev)[(size_t)NE + e];
    } else {
        s = ((const int*)ev)[e];
        d = ((const int*)ev)[(size_t)NE + e];
    }
    int p = atomicAdd(&fillpos[d], 1);
    csr[p] = s;
}

// ---------------- GEMM1: h1 = x @ W1   [100k,256]x[256,64] ----------------
__global__ __launch_bounds__(256) void k_gemm1(const float* __restrict__ x,
                                               const float* __restrict__ W1,
                                               float* __restrict__ h1) {
    __shared__ float xs[16][260];          // pad 260: ty-stride hits distinct banks
    int rowBase = blockIdx.x * 16;
    int t = threadIdx.x;
#pragma unroll
    for (int j = 0; j < 4; ++j) {          // stage 16 rows x 256 cols (float4)
        int fid = j * 256 + t;             // 1024 float4
        int r = fid >> 6, c4 = fid & 63;
        float4 v = *(const float4*)&x[(size_t)(rowBase + r) * IN_DIM + c4 * 4];
        xs[r][c4 * 4 + 0] = v.x; xs[r][c4 * 4 + 1] = v.y;
        xs[r][c4 * 4 + 2] = v.z; xs[r][c4 * 4 + 3] = v.w;
    }
    __syncthreads();
    int ty = t >> 4;                       // row 0..15
    int tx = t & 15;                       // col group: cols 4tx..4tx+3
    float a0 = 0, a1 = 0, a2 = 0, a3 = 0;
#pragma unroll 4
    for (int k = 0; k < IN_DIM; ++k) {
        float xv = xs[ty][k];
        float4 w = *(const float4*)&W1[k * HID + tx * 4];  // L1-broadcast line
        a0 += xv * w.x; a1 += xv * w.y; a2 += xv * w.z; a3 += xv * w.w;
    }
    float4 o; o.x = a0; o.y = a1; o.z = a2; o.w = a3;
    *(float4*)&h1[(size_t)(rowBase + ty) * HID + tx * 4] = o;
}

// ---------------- conv1 aggregate + bias + relu: one wave per node ----------------
__global__ __launch_bounds__(256) void k_agg1(const float* __restrict__ h1,
                                              const int* __restrict__ rowptr,
                                              const int* __restrict__ csr,
                                              const float* __restrict__ dinv,
                                              const float* __restrict__ b1,
                                              float* __restrict__ o1) {
    int wave = threadIdx.x >> 6;
    int lane = threadIdx.x & 63;
    int node = blockIdx.x * 4 + wave;
    if (node >= NN) return;
    float dn = dinv[node];
    float acc = dn * h1[(size_t)node * HID + lane];        // self-loop term
    int i = rowptr[node], end = rowptr[node + 1];
    for (; i + 1 < end; i += 2) {
        int s0 = csr[i], s1 = csr[i + 1];                  // wave-uniform
        float w0 = dinv[s0], w1 = dinv[s1];                // broadcast loads
        float v0 = h1[(size_t)s0 * HID + lane];            // 256B coalesced
        float v1 = h1[(size_t)s1 * HID + lane];
        acc += w0 * v0;
        acc += w1 * v1;
    }
    if (i < end) {
        int s0 = csr[i];
        acc += dinv[s0] * h1[(size_t)s0 * HID + lane];
    }
    float r = dn * acc + b1[lane];
    o1[(size_t)node * HID + lane] = r > 0.0f ? r : 0.0f;
}

// ---------------- GEMM2: h2 = o1 @ W2   [100k,64]x[64,32] ----------------
__global__ __launch_bounds__(256) void k_gemm2(const float* __restrict__ o1,
                                               const float* __restrict__ W2,
                                               float* __restrict__ h2) {
    __shared__ float W2s[HID * ODIM];      // 8 KB
    __shared__ float os[8 * HID];          // 8 rows
    int t = threadIdx.x;
#pragma unroll
    for (int j = 0; j < 2; ++j) {
        int fid = j * 256 + t;             // 512 float4
        *(float4*)&W2s[fid * 4] = *(const float4*)&W2[fid * 4];
    }
    int rowBase = blockIdx.x * 8;
    *(float2*)&os[t * 2] = *(const float2*)&o1[(size_t)rowBase * HID + t * 2];
    __syncthreads();
    int ty = t >> 5, tx = t & 31;
    float acc = 0.0f;
#pragma unroll 8
    for (int k = 0; k < HID; ++k)
        acc += os[ty * HID + k] * W2s[k * ODIM + tx];
    h2[(size_t)(rowBase + ty) * ODIM + tx] = acc;
}

// ---------------- conv2 aggregate + bias: wave = node, 2 edges in flight ----------------
__global__ __launch_bounds__(256) void k_agg2(const float* __restrict__ h2,
                                              const int* __restrict__ rowptr,
                                              const int* __restrict__ csr,
                                              const float* __restrict__ dinv,
                                              const float* __restrict__ b2,
                                              float* __restrict__ z) {
    int wave = threadIdx.x >> 6;
    int lane = threadIdx.x & 63;
    int node = blockIdx.x * 4 + wave;
    if (node >= NN) return;
    int half = lane >> 5;                  // 0/1: alternate edges
    int f = lane & 31;
    float dn = dinv[node];
    float acc = (half == 0) ? dn * h2[(size_t)node * ODIM + f] : 0.0f;
    int start = rowptr[node], end = rowptr[node + 1];
    for (int i = start + half; i < end; i += 2) {
        int s = csr[i];
        acc += dinv[s] * h2[(size_t)s * ODIM + f];
    }
    acc += __shfl_xor(acc, 32, 64);        // combine the two halves
    if (half == 0) z[(size_t)node * ODIM + f] = dn * acc + b2[f];
}

extern "C" void kernel_launch(void* const* d_in, const int* in_sizes, int n_in,
                              void* d_out, int out_size, void* d_ws, size_t ws_size,
                              hipStream_t stream) {
    const float* x  = (const float*)d_in[0];
    const void*  ei = d_in[1];
    const float* W1 = (const float*)d_in[2];
    const float* b1 = (const float*)d_in[3];
    const float* W2 = (const float*)d_in[4];
    const float* b2 = (const float*)d_in[5];
    float* z = (float*)d_out;

    char* w = (char*)d_ws;
    auto alloc = [&](size_t bytes) -> void* {
        void* p = (void*)w;
        w += (bytes + 255) & ~(size_t)255;
        return p;
    };
    int*   cnt     = (int*)  alloc(sizeof(int) * NN);
    int*   flag    = (int*)  alloc(sizeof(int));
    int*   rowptr  = (int*)  alloc(sizeof(int) * (NN + 1));
    int*   fillpos = (int*)  alloc(sizeof(int) * NN);
    int*   bsums   = (int*)  alloc(sizeof(int) * 128);
    float* dinv    = (float*)alloc(sizeof(float) * NN);
    int*   csr     = (int*)  alloc(sizeof(int) * NE);
    float* h1      = (float*)alloc(sizeof(float) * (size_t)NN * HID);
    float* o1      = (float*)alloc(sizeof(float) * (size_t)NN * HID);
    float* h2      = (float*)alloc(sizeof(float) * (size_t)NN * ODIM);
    (void)ws_size; (void)in_sizes; (void)n_in; (void)out_size;  // ~78.4 MB used

    hipMemsetAsync(cnt, 0, sizeof(int) * NN, stream);
    hipMemsetAsync(flag, 0, sizeof(int), stream);

    int nb = (NN + SCAN_ITEMS - 1) / SCAN_ITEMS;   // 98
    k_detect<<<1, 256, 0, stream>>>((const unsigned*)ei, flag);
    k_count <<<(NE + 255) / 256, 256, 0, stream>>>(ei, flag, cnt);
    k_dinv  <<<(NN + 255) / 256, 256, 0, stream>>>(cnt, dinv);
    k_scan1 <<<nb, 256, 0, stream>>>(cnt, bsums);
    k_scan2 <<<1, 64, 0, stream>>>(bsums, rowptr, nb);
    k_scan3 <<<nb, 256, 0, stream>>>(cnt, bsums, rowptr, fillpos);
    k_fill  <<<(NE + 255) / 256, 256, 0, stream>>>(ei, flag, fillpos, csr);
    k_gemm1 <<<NN / 16, 256, 0, stream>>>(x, W1, h1);              // 6250 blocks
    k_agg1  <<<NN / 4, 256, 0, stream>>>(h1, rowptr, csr, dinv, b1, o1);
    k_gemm2 <<<NN / 8, 256, 0, stream>>>(o1, W2, h2);              // 12500 blocks
    k_agg2  <<<NN / 4, 256, 0, stream>>>(h2, rowptr, csr, dinv, b2, z);
}